// Round 3
// baseline (1049.010 us; speedup 1.0000x reference)
//
#include <hip/hip_runtime.h>

#define T_TOK 8192
#define F_IN  2048
#define F_OUT 2048
#define N_EXP 8
#define NT    (F_IN / 64)     // 32 K-tiles of 64
#define MAXMT 32              // max M-tiles/expert (8192/256)

typedef __attribute__((ext_vector_type(8))) short          short8;
typedef __attribute__((ext_vector_type(4))) float          f32x4;
typedef unsigned short ushort;

#define AS1 __attribute__((address_space(1)))
#define AS3 __attribute__((address_space(3)))
#define GLOAD16(g, l) __builtin_amdgcn_global_load_lds((const AS1 unsigned int*)(g), \
                                                       (AS3 unsigned int*)(l), 16, 0, 0)
#define BARRIER() do { asm volatile("" ::: "memory"); __builtin_amdgcn_s_barrier(); \
                       asm volatile("" ::: "memory"); } while (0)

__device__ inline ushort f2bf(float f) {   // RNE
    unsigned u = __float_as_uint(f);
    u += 0x7FFFu + ((u >> 16) & 1u);
    return (ushort)(u >> 16);
}

// ---------------- fp32 -> bf16 bulk convert ----------------
__global__ __launch_bounds__(256) void cvt_kernel(const float* __restrict__ in,
                                                  ushort* __restrict__ out, int n8) {
    for (int i = blockIdx.x * 256 + threadIdx.x; i < n8; i += gridDim.x * 256) {
        const float4 a = ((const float4*)in)[i * 2 + 0];
        const float4 b = ((const float4*)in)[i * 2 + 1];
        uint4 v;
        v.x = f2bf(a.x) | ((unsigned)f2bf(a.y) << 16);
        v.y = f2bf(a.z) | ((unsigned)f2bf(a.w) << 16);
        v.z = f2bf(b.x) | ((unsigned)f2bf(b.y) << 16);
        v.w = f2bf(b.z) | ((unsigned)f2bf(b.w) << 16);
        ((uint4*)out)[i] = v;
    }
}

// ---------------- routing + fused x->bf16 ----------------
__global__ __launch_bounds__(256) void route_kernel(
    const float* __restrict__ x, const float* __restrict__ protos,
    const int* __restrict__ scaling, ushort* __restrict__ xb,
    int* __restrict__ counts, int* __restrict__ lists, float* __restrict__ coeffs)
{
    const int wave = threadIdx.x >> 6;
    const int lane = threadIdx.x & 63;
    const int token = blockIdx.x * 4 + wave;
    if (token >= T_TOK) return;

    const float* xr = x + (size_t)token * F_IN;
    ushort*      xo = xb + (size_t)token * F_IN;
    float s[N_EXP];
    #pragma unroll
    for (int e = 0; e < N_EXP; ++e) s[e] = 0.f;

    for (int c = 0; c < F_IN / 256; ++c) {
        const int off = c * 256 + lane * 4;
        const float4 xv = *(const float4*)(xr + off);
        uint2 bv;
        bv.x = f2bf(xv.x) | ((unsigned)f2bf(xv.y) << 16);
        bv.y = f2bf(xv.z) | ((unsigned)f2bf(xv.w) << 16);
        *(uint2*)(xo + off) = bv;
        #pragma unroll
        for (int e = 0; e < N_EXP; ++e) {
            const float4 pv = *(const float4*)(protos + e * F_IN + off);
            s[e] += xv.x * pv.x + xv.y * pv.y + xv.z * pv.z + xv.w * pv.w;
        }
    }
    #pragma unroll
    for (int e = 0; e < N_EXP; ++e) {
        float v = s[e];
        #pragma unroll
        for (int off = 32; off; off >>= 1) v += __shfl_down(v, off, 64);
        s[e] = v;
    }
    if (lane == 0) {
        float v0 = -1.f; int i0 = 0;
        #pragma unroll
        for (int e = 0; e < N_EXP; ++e) {
            const float a = fabsf(s[e]); s[e] = a;
            if (a > v0) { v0 = a; i0 = e; }
        }
        float v1 = -1.f; int i1 = 0;
        #pragma unroll
        for (int e = 0; e < N_EXP; ++e)
            if (e != i0) { const float a = s[e]; if (a > v1) { v1 = a; i1 = e; } }
        const float ex  = expf(v1 - v0);
        const float inv = 1.f / (1.f + ex);
        const float sc  = (float)(*scaling);
        int slot0 = atomicAdd(&counts[i0], 1);
        lists [i0 * T_TOK + slot0] = token;
        coeffs[i0 * T_TOK + slot0] = sc * inv;
        int slot1 = atomicAdd(&counts[i1], 1);
        lists [i1 * T_TOK + slot1] = token;
        coeffs[i1 * T_TOK + slot1] = sc * ex * inv;
    }
}

// ---------------- grouped bf16 GEMM, 256x256 8-phase (T2+T3+T4+T5) ----------------
__global__ __launch_bounds__(512, 2) void gemm_kernel(
    const ushort* __restrict__ xb, const ushort* __restrict__ Wb,
    const int* __restrict__ counts, const int* __restrict__ lists,
    const float* __restrict__ coeffs, float* __restrict__ out)
{
    const int e     = blockIdx.x >> 5;      // 8 experts x 32 M-tiles
    const int tile  = blockIdx.x & 31;
    const int n_e   = counts[e];
    const int tbase = tile * 256;
    if (tbase >= n_e) return;
    const int o0 = blockIdx.y * 256;

    // A-half qm = rows {qm*64..+63} U {128+qm*64..+63}; B-half qn = col strips qn*32 of each 64-strip
    __shared__ __align__(16) ushort Ald[2][2][128][64];   // [buf][qm][lr][k]  64 KiB
    __shared__ __align__(16) ushort Bld[2][2][128][64];   // [buf][qn][lc][k]  64 KiB

    const int tid  = threadIdx.x;
    const int lane = tid & 63;
    const int wid  = tid >> 6;
    const int wr   = wid >> 2;              // 0..1
    const int wc   = wid & 3;               // 0..3

    // ----- staging setup (T2 swizzle folded into per-lane global src) -----
    const int lr0   = tid >> 3;                                   // 0..63
    const int kElem = ((tid & 7) * 8) ^ (((tid >> 5) & 1) << 4);  // swizzled k-elem 0..63

    const int lbase = e * T_TOK;
    #define TOKP(QM, J) (xb + (size_t)lists[lbase + min(tbase + (J)*128 + (QM)*64 + lr0, n_e - 1)] * F_IN + kElem)
    const ushort* srcA00 = TOKP(0, 0);
    const ushort* srcA01 = TOKP(0, 1);
    const ushort* srcA10 = TOKP(1, 0);
    const ushort* srcA11 = TOKP(1, 1);
    #undef TOKP
    const int bc0 = ((lr0 >> 5)    ) * 64 + (lr0 & 31);           // base col, j=0
    const int bc1 = ((lr0 >> 5) + 2) * 64 + (lr0 & 31);           // base col, j=1
    const ushort* srcB00 = Wb + ((size_t)(e * F_OUT + o0 + bc0     )) * F_IN + kElem;
    const ushort* srcB01 = Wb + ((size_t)(e * F_OUT + o0 + bc1     )) * F_IN + kElem;
    const ushort* srcB10 = Wb + ((size_t)(e * F_OUT + o0 + bc0 + 32)) * F_IN + kElem;
    const ushort* srcB11 = Wb + ((size_t)(e * F_OUT + o0 + bc1 + 32)) * F_IN + kElem;

    #define STAGE_A(QM, T) do { const int _k = (T) * 64;                         \
        ushort* _d = &Ald[(T) & 1][QM][0][0] + wid * 512;                        \
        GLOAD16(srcA##QM##0 + _k, _d); GLOAD16(srcA##QM##1 + _k, _d + 4096); } while (0)
    #define STAGE_B(QN, T) do { const int _k = (T) * 64;                         \
        ushort* _d = &Bld[(T) & 1][QN][0][0] + wid * 512;                        \
        GLOAD16(srcB##QN##0 + _k, _d); GLOAD16(srcB##QN##1 + _k, _d + 4096); } while (0)

    // ----- fragment read offsets (same XOR swizzle on read side) -----
    const int kelb     = ((lane >> 4) * 8) ^ ((lane & 4) ? 16 : 0);
    const int aoffbase = (wr * 64 + (lane & 15)) * 64 + kelb;
    const int boffbase = (wc * 32 + (lane & 15)) * 64 + kelb;

    f32x4 acc[2][2][4][2] = {};

    #define PHASE(QM, QN, STAGE_STMT)                                             \
    {                                                                             \
        short8 af[4][2], bf[2][2];                                                \
        const ushort* Ab = &Ald[buf][QM][0][0] + aoffbase;                        \
        const ushort* Bb = &Bld[buf][QN][0][0] + boffbase;                        \
        _Pragma("unroll") for (int m = 0; m < 4; ++m)                             \
            _Pragma("unroll") for (int kk = 0; kk < 2; ++kk)                      \
                af[m][kk] = *(const short8*)(Ab + m * 1024 + kk * 32);            \
        _Pragma("unroll") for (int n = 0; n < 2; ++n)                             \
            _Pragma("unroll") for (int kk = 0; kk < 2; ++kk)                      \
                bf[n][kk] = *(const short8*)(Bb + n * 1024 + kk * 32);            \
        STAGE_STMT;                                                               \
        BARRIER();                                                                \
        __builtin_amdgcn_s_setprio(1);                                            \
        _Pragma("unroll") for (int kk = 0; kk < 2; ++kk)                          \
            _Pragma("unroll") for (int m = 0; m < 4; ++m)                         \
                _Pragma("unroll") for (int n = 0; n < 2; ++n)                     \
                    acc[QM][QN][m][n] = __builtin_amdgcn_mfma_f32_16x16x32_bf16(  \
                        af[m][kk], bf[n][kk], acc[QM][QN][m][n], 0, 0, 0);        \
        __builtin_amdgcn_s_setprio(0);                                            \
    }

    // ----- prologue: tile0 full + A0/B0 of tile1; guarantee tile0 -----
    STAGE_A(0, 0); STAGE_B(0, 0); STAGE_A(1, 0); STAGE_B(1, 0);
    STAGE_A(0, 1); STAGE_B(0, 1);
    asm volatile("s_waitcnt vmcnt(4)" ::: "memory");
    BARRIER();

    // ----- main loop: 4 phases/K-tile, counted vmcnt at tile boundary -----
    for (int t = 0; t < NT; ++t) {
        const int buf = t & 1;
        PHASE(0, 0, if (t + 1 < NT) STAGE_A(1, t + 1));
        BARRIER();
        PHASE(0, 1, if (t + 1 < NT) STAGE_B(1, t + 1));
        BARRIER();
        PHASE(1, 0, if (t + 2 < NT) STAGE_A(0, t + 2));
        BARRIER();
        PHASE(1, 1, if (t + 2 < NT) STAGE_B(0, t + 2));
        if (t < NT - 2) { asm volatile("s_waitcnt vmcnt(4)" ::: "memory"); }
        else           { asm volatile("s_waitcnt vmcnt(0)" ::: "memory"); }
        BARRIER();
    }

    // ----- epilogue: out[tok][o] += cf * acc  (2 commutative fp32 atomics/elem) -----
    const int rlane = (lane >> 4) * 4;
    const int clane = lane & 15;
    #pragma unroll
    for (int qm = 0; qm < 2; ++qm)
        #pragma unroll
        for (int m = 0; m < 4; ++m)
            #pragma unroll
            for (int rr = 0; rr < 4; ++rr) {
                const int slot = tbase + wr * 128 + qm * 64 + m * 16 + rlane + rr;
                if (slot < n_e) {
                    const int   tok = lists [lbase + slot];
                    const float cf  = coeffs[lbase + slot];
                    float* orow = out + (size_t)tok * F_OUT + o0 + wc * 64 + clane;
                    #pragma unroll
                    for (int qn = 0; qn < 2; ++qn)
                        #pragma unroll
                        for (int n = 0; n < 2; ++n)
                            atomicAdd(orow + qn * 32 + n * 16, cf * acc[qm][qn][m][n][rr]);
                }
            }
}

extern "C" void kernel_launch(void* const* d_in, const int* in_sizes, int n_in,
                              void* d_out, int out_size, void* d_ws, size_t ws_size,
                              hipStream_t stream) {
    const float* x      = (const float*)d_in[0];
    const float* protos = (const float*)d_in[1];
    const float* W      = (const float*)d_in[2];
    const int*   scal   = (const int*)d_in[3];
    float* out = (float*)d_out;

    char* ws = (char*)d_ws;
    int*    counts = (int*)ws;
    int*    lists  = (int*)(ws + 1024);
    float*  coeffs = (float*)(ws + 1024 + (size_t)N_EXP * T_TOK * 4);
    ushort* xb     = (ushort*)(ws + (4u << 20));
    ushort* Wb     = (ushort*)(ws + (4u << 20) + (size_t)T_TOK * F_IN * 2);

    hipMemsetAsync(counts, 0, N_EXP * sizeof(int), stream);
    hipMemsetAsync(d_out, 0, (size_t)out_size * sizeof(float), stream);

    route_kernel<<<T_TOK / 4, 256, 0, stream>>>(x, protos, scal, xb, counts, lists, coeffs);
    cvt_kernel<<<2048, 256, 0, stream>>>(W, Wb, N_EXP * F_OUT * F_IN / 8);

    dim3 grid(N_EXP * MAXMT, F_OUT / 256);
    gemm_kernel<<<grid, 512, 0, stream>>>(xb, Wb, counts, lists, coeffs, out);
}

// Round 4
// 804.506 us; speedup vs baseline: 1.3039x; 1.3039x over previous
//
#include <hip/hip_runtime.h>

#define T_TOK 8192
#define F_IN  2048
#define F_OUT 2048
#define N_EXP 8
#define NT    (F_IN / 64)     // 32 K-tiles of 64
#define MAXMT 32              // max M-tiles/expert

typedef __attribute__((ext_vector_type(8))) short  short8;
typedef __attribute__((ext_vector_type(4))) float  f32x4;
typedef unsigned short ushort;

#define AS1 __attribute__((address_space(1)))
#define AS3 __attribute__((address_space(3)))
#define GLOAD16(g, l) __builtin_amdgcn_global_load_lds((const AS1 unsigned int*)(g), \
                                                       (AS3 unsigned int*)(l), 16, 0, 0)
#define BARRIER() do { asm volatile("" ::: "memory"); __builtin_amdgcn_s_barrier(); \
                       asm volatile("" ::: "memory"); } while (0)

__device__ inline ushort f2bf(float f) {   // RNE
    unsigned u = __float_as_uint(f);
    u += 0x7FFFu + ((u >> 16) & 1u);
    return (ushort)(u >> 16);
}

// ---------------- fp32 -> bf16 bulk convert ----------------
__global__ __launch_bounds__(256) void cvt_kernel(const float* __restrict__ in,
                                                  ushort* __restrict__ out, int n8) {
    for (int i = blockIdx.x * 256 + threadIdx.x; i < n8; i += gridDim.x * 256) {
        const float4 a = ((const float4*)in)[i * 2 + 0];
        const float4 b = ((const float4*)in)[i * 2 + 1];
        uint4 v;
        v.x = f2bf(a.x) | ((unsigned)f2bf(a.y) << 16);
        v.y = f2bf(a.z) | ((unsigned)f2bf(a.w) << 16);
        v.z = f2bf(b.x) | ((unsigned)f2bf(b.y) << 16);
        v.w = f2bf(b.z) | ((unsigned)f2bf(b.w) << 16);
        ((uint4*)out)[i] = v;
    }
}

// ---------------- routing + fused x->bf16 ----------------
__global__ __launch_bounds__(256) void route_kernel(
    const float* __restrict__ x, const float* __restrict__ protos,
    const int* __restrict__ scaling, ushort* __restrict__ xb,
    int* __restrict__ counts, int* __restrict__ lists, float* __restrict__ coeffs)
{
    const int wave = threadIdx.x >> 6;
    const int lane = threadIdx.x & 63;
    const int token = blockIdx.x * 4 + wave;
    if (token >= T_TOK) return;

    const float* xr = x + (size_t)token * F_IN;
    ushort*      xo = xb + (size_t)token * F_IN;
    float s[N_EXP];
    #pragma unroll
    for (int e = 0; e < N_EXP; ++e) s[e] = 0.f;

    for (int c = 0; c < F_IN / 256; ++c) {
        const int off = c * 256 + lane * 4;
        const float4 xv = *(const float4*)(xr + off);
        uint2 bv;
        bv.x = f2bf(xv.x) | ((unsigned)f2bf(xv.y) << 16);
        bv.y = f2bf(xv.z) | ((unsigned)f2bf(xv.w) << 16);
        *(uint2*)(xo + off) = bv;
        #pragma unroll
        for (int e = 0; e < N_EXP; ++e) {
            const float4 pv = *(const float4*)(protos + e * F_IN + off);
            s[e] += xv.x * pv.x + xv.y * pv.y + xv.z * pv.z + xv.w * pv.w;
        }
    }
    #pragma unroll
    for (int e = 0; e < N_EXP; ++e) {
        float v = s[e];
        #pragma unroll
        for (int off = 32; off; off >>= 1) v += __shfl_down(v, off, 64);
        s[e] = v;
    }
    if (lane == 0) {
        float v0 = -1.f; int i0 = 0;
        #pragma unroll
        for (int e = 0; e < N_EXP; ++e) {
            const float a = fabsf(s[e]); s[e] = a;
            if (a > v0) { v0 = a; i0 = e; }
        }
        float v1 = -1.f; int i1 = 0;
        #pragma unroll
        for (int e = 0; e < N_EXP; ++e)
            if (e != i0) { const float a = s[e]; if (a > v1) { v1 = a; i1 = e; } }
        const float ex  = expf(v1 - v0);
        const float inv = 1.f / (1.f + ex);
        const float sc  = (float)(*scaling);
        int slot0 = atomicAdd(&counts[i0], 1);
        lists [i0 * T_TOK + slot0] = token;
        coeffs[i0 * T_TOK + slot0] = sc * inv;
        int slot1 = atomicAdd(&counts[i1], 1);
        lists [i1 * T_TOK + slot1] = token;
        coeffs[i1 * T_TOK + slot1] = sc * ex * inv;
    }
}

// ---- grouped bf16 GEMM, 256x256, 8-phase, 3-bit XOR swizzle + frag reuse ----
__global__ __launch_bounds__(512, 2) void gemm_kernel(
    const ushort* __restrict__ xb, const ushort* __restrict__ Wb,
    const int* __restrict__ counts, const int* __restrict__ lists,
    const float* __restrict__ coeffs, float* __restrict__ out)
{
    const int e     = blockIdx.x >> 5;
    const int tile  = blockIdx.x & 31;
    const int n_e   = counts[e];
    const int tbase = tile * 256;
    if (tbase >= n_e) return;
    const int o0 = blockIdx.y * 256;

    __shared__ __align__(16) ushort Ald[2][2][128][64];   // [buf][half][row][k]
    __shared__ __align__(16) ushort Bld[2][2][128][64];

    const int tid  = threadIdx.x;
    const int lane = tid & 63;
    const int wid  = tid >> 6;
    const int wr   = wid >> 2;              // 0..1
    const int wc   = wid & 3;               // 0..3

    // ----- staging: linear LDS dest; 3-bit swizzle folded into global src -----
    const int lr0   = tid >> 3;                              // row 0..63 in half-tile
    const int kElem = ((tid & 7) ^ (lr0 & 7)) * 8;           // swizzled k-octet

    const int lbase = e * T_TOK;
    #define TOKP(QM, J) (xb + (size_t)lists[lbase + min(tbase + (J)*128 + (QM)*64 + lr0, n_e - 1)] * F_IN + kElem)
    const ushort* srcA00 = TOKP(0, 0);
    const ushort* srcA01 = TOKP(0, 1);
    const ushort* srcA10 = TOKP(1, 0);
    const ushort* srcA11 = TOKP(1, 1);
    #undef TOKP
    const int bc0 = ((lr0 >> 5)    ) * 64 + (lr0 & 31);
    const int bc1 = ((lr0 >> 5) + 2) * 64 + (lr0 & 31);
    const ushort* srcB00 = Wb + ((size_t)(e * F_OUT + o0 + bc0     )) * F_IN + kElem;
    const ushort* srcB01 = Wb + ((size_t)(e * F_OUT + o0 + bc1     )) * F_IN + kElem;
    const ushort* srcB10 = Wb + ((size_t)(e * F_OUT + o0 + bc0 + 32)) * F_IN + kElem;
    const ushort* srcB11 = Wb + ((size_t)(e * F_OUT + o0 + bc1 + 32)) * F_IN + kElem;

    #define STAGE_A(QM, T) do { const int _k = (T) * 64;                         \
        ushort* _d = &Ald[(T) & 1][QM][0][0] + wid * 512;                        \
        GLOAD16(srcA##QM##0 + _k, _d); GLOAD16(srcA##QM##1 + _k, _d + 4096); } while (0)
    #define STAGE_B(QN, T) do { const int _k = (T) * 64;                         \
        ushort* _d = &Bld[(T) & 1][QN][0][0] + wid * 512;                        \
        GLOAD16(srcB##QN##0 + _k, _d); GLOAD16(srcB##QN##1 + _k, _d + 4096); } while (0)

    // ----- fragment reads: same 3-bit swizzle (row&7 == lane&7 for all reads) -----
    const int octx8    = ((lane >> 4) ^ (lane & 7)) * 8;
    const int aoffbase = (wr * 64 + (lane & 15)) * 64 + octx8;
    const int boffbase = (wc * 32 + (lane & 15)) * 64 + octx8;

    #define LOAD_A(DST, HALF) do { const ushort* _h = &Ald[buf][HALF][0][0];      \
        _Pragma("unroll") for (int m = 0; m < 4; ++m) {                           \
            DST[m][0] = *(const short8*)(_h + (aoffbase + m * 1024));             \
            DST[m][1] = *(const short8*)(_h + ((aoffbase + m * 1024) ^ 32)); } } while (0)
    #define LOAD_B(DST, HALF) do { const ushort* _h = &Bld[buf][HALF][0][0];      \
        _Pragma("unroll") for (int n = 0; n < 2; ++n) {                           \
            DST[n][0] = *(const short8*)(_h + (boffbase + n * 1024));             \
            DST[n][1] = *(const short8*)(_h + ((boffbase + n * 1024) ^ 32)); } } while (0)

    f32x4 acc[2][2][4][2] = {};

    #define MMA(QM, QN, AF, BF) do { BARRIER();                                   \
        __builtin_amdgcn_s_setprio(1);                                            \
        _Pragma("unroll") for (int kk = 0; kk < 2; ++kk)                          \
            _Pragma("unroll") for (int m = 0; m < 4; ++m)                         \
                _Pragma("unroll") for (int n = 0; n < 2; ++n)                     \
                    acc[QM][QN][m][n] = __builtin_amdgcn_mfma_f32_16x16x32_bf16(  \
                        AF[m][kk], BF[n][kk], acc[QM][QN][m][n], 0, 0, 0);        \
        __builtin_amdgcn_s_setprio(0); } while (0)

    // ----- prologue: A0/B0/A1/B1 of tile0 + A0/B0 of tile1; drain first 8 -----
    STAGE_A(0, 0); STAGE_B(0, 0); STAGE_A(1, 0); STAGE_B(1, 0);
    STAGE_A(0, 1); STAGE_B(0, 1);
    asm volatile("s_waitcnt vmcnt(4)" ::: "memory");
    BARRIER();

    // ----- main loop: 4 phases/K-tile, frag-reuse, counted vmcnt at boundary -----
    for (int t = 0; t < NT; ++t) {
        const int buf = t & 1;
        short8 af[4][2], bf0[2][2], bf1[2][2];

        LOAD_A(af, 0); LOAD_B(bf0, 0);          // P1: 12 reads
        if (t + 1 < NT) STAGE_A(1, t + 1);
        MMA(0, 0, af, bf0); BARRIER();

        LOAD_B(bf1, 1);                         // P2: 4 reads (af reused)
        if (t + 1 < NT) STAGE_B(1, t + 1);
        MMA(0, 1, af, bf1); BARRIER();

        LOAD_A(af, 1);                          // P3: 8 reads (bf1 reused)
        if (t + 2 < NT) STAGE_A(0, t + 2);
        MMA(1, 1, af, bf1); BARRIER();

        if (t + 2 < NT) STAGE_B(0, t + 2);      // P4: 0 reads (af, bf0 reused)
        MMA(1, 0, af, bf0);
        if (t < NT - 2) asm volatile("s_waitcnt vmcnt(4)" ::: "memory");
        else            asm volatile("s_waitcnt vmcnt(0)" ::: "memory");
        BARRIER();
    }

    // ----- epilogue: out[tok][o] += cf * acc -----
    const int rlane = (lane >> 4) * 4;
    const int clane = lane & 15;
    #pragma unroll
    for (int qm = 0; qm < 2; ++qm)
        #pragma unroll
        for (int m = 0; m < 4; ++m)
            #pragma unroll
            for (int rr = 0; rr < 4; ++rr) {
                const int slot = tbase + wr * 128 + qm * 64 + m * 16 + rlane + rr;
                if (slot < n_e) {
                    const int   tok = lists [lbase + slot];
                    const float cf  = coeffs[lbase + slot];
                    float* orow = out + (size_t)tok * F_OUT + o0 + wc * 64 + clane;
                    #pragma unroll
                    for (int qn = 0; qn < 2; ++qn)
                        #pragma unroll
                        for (int n = 0; n < 2; ++n)
                            atomicAdd(orow + qn * 32 + n * 16, cf * acc[qm][qn][m][n][rr]);
                }
            }
}

extern "C" void kernel_launch(void* const* d_in, const int* in_sizes, int n_in,
                              void* d_out, int out_size, void* d_ws, size_t ws_size,
                              hipStream_t stream) {
    const float* x      = (const float*)d_in[0];
    const float* protos = (const float*)d_in[1];
    const float* W      = (const float*)d_in[2];
    const int*   scal   = (const int*)d_in[3];
    float* out = (float*)d_out;

    char* ws = (char*)d_ws;
    int*    counts = (int*)ws;
    int*    lists  = (int*)(ws + 1024);
    float*  coeffs = (float*)(ws + 1024 + (size_t)N_EXP * T_TOK * 4);
    ushort* xb     = (ushort*)(ws + (4u << 20));
    ushort* Wb     = (ushort*)(ws + (4u << 20) + (size_t)T_TOK * F_IN * 2);

    hipMemsetAsync(counts, 0, N_EXP * sizeof(int), stream);
    hipMemsetAsync(d_out, 0, (size_t)out_size * sizeof(float), stream);

    route_kernel<<<T_TOK / 4, 256, 0, stream>>>(x, protos, scal, xb, counts, lists, coeffs);
    cvt_kernel<<<2048, 256, 0, stream>>>(W, Wb, N_EXP * F_OUT * F_IN / 8);

    dim3 grid(N_EXP * MAXMT, F_OUT / 256);
    gemm_kernel<<<grid, 512, 0, stream>>>(xb, Wb, counts, lists, coeffs, out);
}

// Round 5
// 460.089 us; speedup vs baseline: 2.2800x; 1.7486x over previous
//
#include <hip/hip_runtime.h>

#define T_TOK 8192
#define F_IN  2048
#define F_OUT 2048
#define N_EXP 8
#define NKS   (F_IN / 64)      // 32 K-steps of 64
#define MAXTILES 144

typedef __attribute__((ext_vector_type(8))) short    short8;
typedef __attribute__((ext_vector_type(4))) float    f32x4;
typedef __attribute__((ext_vector_type(8))) _Float16 half8;
typedef unsigned short ushort;

#define AS1 __attribute__((address_space(1)))
#define AS3 __attribute__((address_space(3)))
#define GLOAD16(g, l) __builtin_amdgcn_global_load_lds((const AS1 unsigned int*)(g), \
                                                       (AS3 unsigned int*)(l), 16, 0, 0)

__device__ inline ushort f2bf(float f) {   // RNE
    unsigned u = __float_as_uint(f);
    u += 0x7FFFu + ((u >> 16) & 1u);
    return (ushort)(u >> 16);
}

// ---------------- fp32 -> bf16 bulk convert (W) ----------------
__global__ __launch_bounds__(256) void cvt_kernel(const float* __restrict__ in,
                                                  ushort* __restrict__ out, int n8) {
    for (int i = blockIdx.x * 256 + threadIdx.x; i < n8; i += gridDim.x * 256) {
        const float4 a = ((const float4*)in)[i * 2 + 0];
        const float4 b = ((const float4*)in)[i * 2 + 1];
        uint4 v;
        v.x = f2bf(a.x) | ((unsigned)f2bf(a.y) << 16);
        v.y = f2bf(a.z) | ((unsigned)f2bf(a.w) << 16);
        v.z = f2bf(b.x) | ((unsigned)f2bf(b.y) << 16);
        v.w = f2bf(b.z) | ((unsigned)f2bf(b.w) << 16);
        ((uint4*)out)[i] = v;
    }
}

// ---------------- routing + fused x->bf16 + inverse map ----------------
__global__ __launch_bounds__(256) void route_kernel(
    const float* __restrict__ x, const float* __restrict__ protos,
    const int* __restrict__ scaling, ushort* __restrict__ xb,
    int* __restrict__ counts, int* __restrict__ lists, float* __restrict__ coeffs,
    int* __restrict__ pos)
{
    const int wave = threadIdx.x >> 6;
    const int lane = threadIdx.x & 63;
    const int token = blockIdx.x * 4 + wave;
    if (token >= T_TOK) return;

    const float* xr = x + (size_t)token * F_IN;
    ushort*      xo = xb + (size_t)token * F_IN;
    float s[N_EXP];
    #pragma unroll
    for (int e = 0; e < N_EXP; ++e) s[e] = 0.f;

    for (int c = 0; c < F_IN / 256; ++c) {
        const int off = c * 256 + lane * 4;
        const float4 xv = *(const float4*)(xr + off);
        uint2 bv;
        bv.x = f2bf(xv.x) | ((unsigned)f2bf(xv.y) << 16);
        bv.y = f2bf(xv.z) | ((unsigned)f2bf(xv.w) << 16);
        *(uint2*)(xo + off) = bv;
        #pragma unroll
        for (int e = 0; e < N_EXP; ++e) {
            const float4 pv = *(const float4*)(protos + e * F_IN + off);
            s[e] += xv.x * pv.x + xv.y * pv.y + xv.z * pv.z + xv.w * pv.w;
        }
    }
    #pragma unroll
    for (int e = 0; e < N_EXP; ++e) {
        float v = s[e];
        #pragma unroll
        for (int off = 32; off; off >>= 1) v += __shfl_down(v, off, 64);
        s[e] = v;
    }
    if (lane == 0) {
        float v0 = -1.f; int i0 = 0;
        #pragma unroll
        for (int e = 0; e < N_EXP; ++e) {
            const float a = fabsf(s[e]); s[e] = a;
            if (a > v0) { v0 = a; i0 = e; }
        }
        float v1 = -1.f; int i1 = 0;
        #pragma unroll
        for (int e = 0; e < N_EXP; ++e)
            if (e != i0) { const float a = s[e]; if (a > v1) { v1 = a; i1 = e; } }
        const float ex  = expf(v1 - v0);
        const float inv = 1.f / (1.f + ex);
        const float sc  = (float)(*scaling);
        int slot0 = atomicAdd(&counts[i0], 1);
        lists [i0 * T_TOK + slot0] = token;
        coeffs[i0 * T_TOK + slot0] = sc * inv;
        pos[token * 2 + 0] = i0 * T_TOK + slot0;
        int slot1 = atomicAdd(&counts[i1], 1);
        lists [i1 * T_TOK + slot1] = token;
        coeffs[i1 * T_TOK + slot1] = sc * ex * inv;
        pos[token * 2 + 1] = i1 * T_TOK + slot1;
    }
}

// ---------------- plan: prefix bases + flat tile descriptors ----------------
__global__ void plan_kernel(const int* __restrict__ counts, int* __restrict__ pbase,
                            int* __restrict__ ntiles, int* __restrict__ desc) {
    if (threadIdx.x == 0) {
        int pb = 0, t = 0;
        for (int e = 0; e < N_EXP; ++e) {
            pbase[e] = pb;
            const int ne = counts[e];
            const int nt = (ne + 127) >> 7;
            for (int i = 0; i < nt; ++i) desc[t++] = (e << 8) | i;
            pb += ne;
        }
        *ntiles = t;
    }
}

// ---- grouped bf16 GEMM, 128x128, BK=64, 2-phase, swizzled LDS, no atomics ----
__global__ __launch_bounds__(256, 3) void gemm_kernel(
    const ushort* __restrict__ xb, const ushort* __restrict__ Wb,
    const int* __restrict__ counts, const int* __restrict__ lists,
    const int* __restrict__ pbase, const int* __restrict__ ntiles,
    const int* __restrict__ desc, _Float16* __restrict__ delta)
{
    if (blockIdx.x >= *ntiles) return;
    const int d     = desc[blockIdx.x];
    const int e     = d >> 8;
    const int tile  = d & 255;
    const int n_e   = counts[e];
    const int tbase = tile << 7;
    const int o0    = blockIdx.y * 128;
    const int prow0 = pbase[e] + tbase;

    __shared__ __align__(16) ushort As[128 * 64];   // [row][koct^ (row&7)] 16 KiB
    __shared__ __align__(16) ushort Bs[128 * 64];

    const int tid  = threadIdx.x;
    const int lane = tid & 63;
    const int wid  = tid >> 6;
    const int wr   = wid >> 1, wc = wid & 1;

    // ---- staging: per-lane pre-swizzled global src, linear LDS dest ----
    const int ksrc = ((lane & 7) ^ (lane >> 3)) * 8;     // swizzled k-octet (ushorts)
    const ushort* srcA[4];
    const ushort* srcB[4];
    #pragma unroll
    for (int g = 0; g < 4; ++g) {
        const int row  = g * 32 + wid * 8 + (lane >> 3);
        const int slot = min(tbase + row, n_e - 1);
        srcA[g] = xb + (size_t)lists[e * T_TOK + slot] * F_IN + ksrc;
        srcB[g] = Wb + ((size_t)e * F_OUT + o0 + row) * F_IN + ksrc;
    }

    // ---- fragment read bases (same XOR on read side) ----
    const int octx8 = ((lane >> 4) ^ (lane & 7)) * 8;
    const int ai    = (wr * 64 + (lane & 15)) * 64 + octx8;
    const int bi    = (wc * 64 + (lane & 15)) * 64 + octx8;

    f32x4 acc[4][4] = {};

    for (int ks = 0; ks < NKS; ++ks) {
        __syncthreads();                       // prev-step LDS reads complete
        #pragma unroll
        for (int g = 0; g < 4; ++g) {
            GLOAD16(srcA[g], As + (g * 32 + wid * 8) * 64);
            GLOAD16(srcB[g], Bs + (g * 32 + wid * 8) * 64);
            srcA[g] += 64; srcB[g] += 64;
        }
        __syncthreads();                       // vmcnt(0) drain: staged data visible

        short8 a[4][2], b[4][2];
        #pragma unroll
        for (int m = 0; m < 4; ++m) {
            a[m][0] = *(const short8*)(As + (ai + m * 1024));
            a[m][1] = *(const short8*)(As + ((ai + m * 1024) ^ 32));
        }
        #pragma unroll
        for (int n = 0; n < 4; ++n) {
            b[n][0] = *(const short8*)(Bs + (bi + n * 1024));
            b[n][1] = *(const short8*)(Bs + ((bi + n * 1024) ^ 32));
        }
        #pragma unroll
        for (int kk = 0; kk < 2; ++kk)
            #pragma unroll
            for (int m = 0; m < 4; ++m)
                #pragma unroll
                for (int n = 0; n < 4; ++n)
                    acc[m][n] = __builtin_amdgcn_mfma_f32_16x16x32_bf16(
                        a[m][kk], b[n][kk], acc[m][n], 0, 0, 0);
    }

    // ---- epilogue: single-writer fp16 delta rows (no atomics) ----
    const int rl = (lane >> 4) * 4;
    const int cl = lane & 15;
    #pragma unroll
    for (int m = 0; m < 4; ++m)
        #pragma unroll
        for (int rr = 0; rr < 4; ++rr) {
            const int srow = wr * 64 + m * 16 + rl + rr;
            if (tbase + srow < n_e) {
                _Float16* drow = delta + (size_t)(prow0 + srow) * F_OUT + o0 + wc * 64 + cl;
                #pragma unroll
                for (int n = 0; n < 4; ++n)
                    drow[n * 16] = (_Float16)acc[m][n][rr];
            }
        }
}

// ---------------- combine: out[tok] = cf0*delta[p0] + cf1*delta[p1] ----------------
__global__ __launch_bounds__(256) void combine_kernel(
    const _Float16* __restrict__ delta, const int* __restrict__ pos,
    const float* __restrict__ coeffs, const int* __restrict__ pbase,
    float* __restrict__ out)
{
    const int tok = blockIdx.x;
    const int id0 = pos[tok * 2 + 0];
    const int id1 = pos[tok * 2 + 1];
    const float cf0 = coeffs[id0];
    const float cf1 = coeffs[id1];
    const int r0 = pbase[id0 >> 13] + (id0 & (T_TOK - 1));
    const int r1 = pbase[id1 >> 13] + (id1 & (T_TOK - 1));
    const int c  = threadIdx.x * 8;

    const half8 a = *(const half8*)(delta + (size_t)r0 * F_OUT + c);
    const half8 b = *(const half8*)(delta + (size_t)r1 * F_OUT + c);
    float4 o0, o1;
    o0.x = cf0 * (float)a[0] + cf1 * (float)b[0];
    o0.y = cf0 * (float)a[1] + cf1 * (float)b[1];
    o0.z = cf0 * (float)a[2] + cf1 * (float)b[2];
    o0.w = cf0 * (float)a[3] + cf1 * (float)b[3];
    o1.x = cf0 * (float)a[4] + cf1 * (float)b[4];
    o1.y = cf0 * (float)a[5] + cf1 * (float)b[5];
    o1.z = cf0 * (float)a[6] + cf1 * (float)b[6];
    o1.w = cf0 * (float)a[7] + cf1 * (float)b[7];
    float* op = out + (size_t)tok * F_OUT + c;
    *(float4*)(op)     = o0;
    *(float4*)(op + 4) = o1;
}

extern "C" void kernel_launch(void* const* d_in, const int* in_sizes, int n_in,
                              void* d_out, int out_size, void* d_ws, size_t ws_size,
                              hipStream_t stream) {
    const float* x      = (const float*)d_in[0];
    const float* protos = (const float*)d_in[1];
    const float* W      = (const float*)d_in[2];
    const int*   scal   = (const int*)d_in[3];
    float* out = (float*)d_out;

    char* ws = (char*)d_ws;
    int*      counts = (int*)(ws + 0);
    int*      pbase  = (int*)(ws + 64);
    int*      ntiles = (int*)(ws + 128);
    int*      desc   = (int*)(ws + 256);
    int*      pos    = (int*)(ws + 65536);                    // 64 KB
    int*      lists  = (int*)(ws + 262144);                   // 256 KB
    float*    coeffs = (float*)(ws + 524288);                 // 256 KB
    ushort*   xb     = (ushort*)(ws + (1ull << 20));          // 32 MB
    ushort*   Wb     = (ushort*)(ws + (36ull << 20));         // 64 MB
    _Float16* delta  = (_Float16*)(ws + (104ull << 20));      // 64 MB, high-water 168 MB

    hipMemsetAsync(counts, 0, N_EXP * sizeof(int), stream);

    cvt_kernel<<<2048, 256, 0, stream>>>(W, Wb, N_EXP * F_OUT * F_IN / 8);
    route_kernel<<<T_TOK / 4, 256, 0, stream>>>(x, protos, scal, xb, counts, lists, coeffs, pos);
    plan_kernel<<<1, 64, 0, stream>>>(counts, pbase, ntiles, desc);

    dim3 grid(MAXTILES, F_OUT / 128);
    gemm_kernel<<<grid, 256, 0, stream>>>(xb, Wb, counts, lists, pbase, ntiles, desc, delta);

    combine_kernel<<<T_TOK, 256, 0, stream>>>(delta, pos, coeffs, pbase, out);
}

// Round 6
// 339.065 us; speedup vs baseline: 3.0938x; 1.3569x over previous
//
#include <hip/hip_runtime.h>

#define T_TOK 8192
#define F_IN  2048
#define F_OUT 2048
#define N_EXP 8
#define NKS   (F_IN / 64)      // 32 K-steps of 64
#define MAXTILES 144
#define RT_TPB 16              // tokens per routing block

typedef __attribute__((ext_vector_type(8))) short    short8;
typedef __attribute__((ext_vector_type(4))) float    f32x4;
typedef __attribute__((ext_vector_type(8))) _Float16 half8;
typedef unsigned short ushort;

#define AS1 __attribute__((address_space(1)))
#define AS3 __attribute__((address_space(3)))
#define GLOAD16(g, l) __builtin_amdgcn_global_load_lds((const AS1 unsigned int*)(g), \
                                                       (AS3 unsigned int*)(l), 16, 0, 0)

__device__ inline ushort f2bf(float f) {   // RNE
    unsigned u = __float_as_uint(f);
    u += 0x7FFFu + ((u >> 16) & 1u);
    return (ushort)(u >> 16);
}

// ---------------- fp32 -> bf16 bulk convert (W) ----------------
__global__ __launch_bounds__(256) void cvt_kernel(const float* __restrict__ in,
                                                  ushort* __restrict__ out, int n8) {
    for (int i = blockIdx.x * 256 + threadIdx.x; i < n8; i += gridDim.x * 256) {
        const float4 a = ((const float4*)in)[i * 2 + 0];
        const float4 b = ((const float4*)in)[i * 2 + 1];
        uint4 v;
        v.x = f2bf(a.x) | ((unsigned)f2bf(a.y) << 16);
        v.y = f2bf(a.z) | ((unsigned)f2bf(a.w) << 16);
        v.z = f2bf(b.x) | ((unsigned)f2bf(b.y) << 16);
        v.w = f2bf(b.z) | ((unsigned)f2bf(b.w) << 16);
        ((uint4*)out)[i] = v;
    }
}

// ---------------- routing + fused x->bf16, block-aggregated atomics ----------------
__device__ inline void top2_store(const float* s, int ti, float sc,
                                  int* sh_ei, float (*sh_cf)[2]) {
    float v0 = -1.f; int i0 = 0;
    #pragma unroll
    for (int e = 0; e < N_EXP; ++e) {
        const float a = fabsf(s[e]);
        if (a > v0) { v0 = a; i0 = e; }
    }
    float v1 = -1.f; int i1 = 0;
    #pragma unroll
    for (int e = 0; e < N_EXP; ++e) {
        const float a = fabsf(s[e]);
        if (e != i0 && a > v1) { v1 = a; i1 = e; }
    }
    const float ex  = expf(v1 - v0);
    const float inv = 1.f / (1.f + ex);
    sh_ei[ti]    = i0 | (i1 << 16);
    sh_cf[ti][0] = sc * inv;
    sh_cf[ti][1] = sc * ex * inv;
}

__global__ __launch_bounds__(256) void route_kernel(
    const float* __restrict__ x, const float* __restrict__ protos,
    const int* __restrict__ scaling, ushort* __restrict__ xb,
    int* __restrict__ counts, int* __restrict__ lists, float* __restrict__ coeffs,
    int* __restrict__ pos)
{
    __shared__ int   sh_ei[RT_TPB];
    __shared__ float sh_cf[RT_TPB][2];
    __shared__ int   sh_base[N_EXP];

    const int wave = threadIdx.x >> 6;
    const int lane = threadIdx.x & 63;
    const float sc = (float)(*scaling);

    // each wave: 4 tokens, processed as 2 pairs (2 HBM streams, shared proto loads)
    for (int pr = 0; pr < 2; ++pr) {
        const int ti0  = wave * 4 + pr * 2;
        const int tok0 = blockIdx.x * RT_TPB + ti0;
        const float* xr0 = x  + (size_t)tok0 * F_IN;
        const float* xr1 = xr0 + F_IN;
        ushort*      xo0 = xb + (size_t)tok0 * F_IN;
        ushort*      xo1 = xo0 + F_IN;

        float s0[N_EXP] = {}, s1[N_EXP] = {};
        for (int c = 0; c < F_IN / 256; ++c) {
            const int off = c * 256 + lane * 4;
            const float4 a = *(const float4*)(xr0 + off);
            const float4 b = *(const float4*)(xr1 + off);
            uint2 ba, bb;
            ba.x = f2bf(a.x) | ((unsigned)f2bf(a.y) << 16);
            ba.y = f2bf(a.z) | ((unsigned)f2bf(a.w) << 16);
            bb.x = f2bf(b.x) | ((unsigned)f2bf(b.y) << 16);
            bb.y = f2bf(b.z) | ((unsigned)f2bf(b.w) << 16);
            *(uint2*)(xo0 + off) = ba;
            *(uint2*)(xo1 + off) = bb;
            #pragma unroll
            for (int e = 0; e < N_EXP; ++e) {
                const float4 pv = *(const float4*)(protos + e * F_IN + off);
                s0[e] += a.x * pv.x + a.y * pv.y + a.z * pv.z + a.w * pv.w;
                s1[e] += b.x * pv.x + b.y * pv.y + b.z * pv.z + b.w * pv.w;
            }
        }
        #pragma unroll
        for (int e = 0; e < N_EXP; ++e) {
            float v0 = s0[e], v1 = s1[e];
            #pragma unroll
            for (int off = 32; off; off >>= 1) {
                v0 += __shfl_down(v0, off, 64);
                v1 += __shfl_down(v1, off, 64);
            }
            s0[e] = v0; s1[e] = v1;
        }
        if (lane == 0) {
            top2_store(s0, ti0,     sc, sh_ei, sh_cf);
            top2_store(s1, ti0 + 1, sc, sh_ei, sh_cf);
        }
    }
    __syncthreads();

    // ---- aggregation: one wave, 32 (token,slot) pairs, 8 atomics/block ----
    if (threadIdx.x < 64) {
        const int  p      = threadIdx.x;
        const bool active = p < RT_TPB * 2;
        const int  ti = p >> 1, j = p & 1;
        const int  e  = active ? ((sh_ei[ti] >> (j * 16)) & 0xffff) : 0xff;
        int rank = 0;
        #pragma unroll
        for (int ee = 0; ee < N_EXP; ++ee) {
            const unsigned long long m = __ballot(active && (e == ee));
            if (e == ee)
                rank = __popcll(m & ((1ull << p) - 1ull));
            if (p == ee && m != 0ull)
                sh_base[ee] = atomicAdd(&counts[ee], (int)__popcll(m));
        }
        if (active) {
            const int position = sh_base[e] + rank;   // wave-ordered LDS: write precedes read
            const int gidx  = e * T_TOK + position;
            const int token = blockIdx.x * RT_TPB + ti;
            lists [gidx] = token;
            coeffs[gidx] = sh_cf[ti][j];
            pos[token * 2 + j] = gidx;
        }
    }
}

// ---------------- plan: prefix bases + flat tile descriptors ----------------
__global__ void plan_kernel(const int* __restrict__ counts, int* __restrict__ pbase,
                            int* __restrict__ ntiles, int* __restrict__ desc) {
    if (threadIdx.x == 0) {
        int pb = 0, t = 0;
        for (int e = 0; e < N_EXP; ++e) {
            pbase[e] = pb;
            const int ne = counts[e];
            const int nt = (ne + 127) >> 7;
            for (int i = 0; i < nt; ++i) desc[t++] = (e << 8) | i;
            pb += ne;
        }
        *ntiles = t;
    }
}

// ---- grouped bf16 GEMM, 128x128, BK=64, 2-phase, swizzled LDS, no atomics ----
__global__ __launch_bounds__(256, 3) void gemm_kernel(
    const ushort* __restrict__ xb, const ushort* __restrict__ Wb,
    const int* __restrict__ counts, const int* __restrict__ lists,
    const int* __restrict__ pbase, const int* __restrict__ ntiles,
    const int* __restrict__ desc, _Float16* __restrict__ delta)
{
    if (blockIdx.x >= *ntiles) return;
    const int d     = desc[blockIdx.x];
    const int e     = d >> 8;
    const int tile  = d & 255;
    const int n_e   = counts[e];
    const int tbase = tile << 7;
    const int o0    = blockIdx.y * 128;
    const int prow0 = pbase[e] + tbase;

    __shared__ __align__(16) ushort As[128 * 64];
    __shared__ __align__(16) ushort Bs[128 * 64];

    const int tid  = threadIdx.x;
    const int lane = tid & 63;
    const int wid  = tid >> 6;
    const int wr   = wid >> 1, wc = wid & 1;

    const int ksrc = ((lane & 7) ^ (lane >> 3)) * 8;
    const ushort* srcA[4];
    const ushort* srcB[4];
    #pragma unroll
    for (int g = 0; g < 4; ++g) {
        const int row  = g * 32 + wid * 8 + (lane >> 3);
        const int slot = min(tbase + row, n_e - 1);
        srcA[g] = xb + (size_t)lists[e * T_TOK + slot] * F_IN + ksrc;
        srcB[g] = Wb + ((size_t)e * F_OUT + o0 + row) * F_IN + ksrc;
    }

    const int octx8 = ((lane >> 4) ^ (lane & 7)) * 8;
    const int ai    = (wr * 64 + (lane & 15)) * 64 + octx8;
    const int bi    = (wc * 64 + (lane & 15)) * 64 + octx8;

    f32x4 acc[4][4] = {};

    for (int ks = 0; ks < NKS; ++ks) {
        __syncthreads();
        #pragma unroll
        for (int g = 0; g < 4; ++g) {
            GLOAD16(srcA[g], As + (g * 32 + wid * 8) * 64);
            GLOAD16(srcB[g], Bs + (g * 32 + wid * 8) * 64);
            srcA[g] += 64; srcB[g] += 64;
        }
        __syncthreads();

        short8 a[4][2], b[4][2];
        #pragma unroll
        for (int m = 0; m < 4; ++m) {
            a[m][0] = *(const short8*)(As + (ai + m * 1024));
            a[m][1] = *(const short8*)(As + ((ai + m * 1024) ^ 32));
        }
        #pragma unroll
        for (int n = 0; n < 4; ++n) {
            b[n][0] = *(const short8*)(Bs + (bi + n * 1024));
            b[n][1] = *(const short8*)(Bs + ((bi + n * 1024) ^ 32));
        }
        #pragma unroll
        for (int kk = 0; kk < 2; ++kk)
            #pragma unroll
            for (int m = 0; m < 4; ++m)
                #pragma unroll
                for (int n = 0; n < 4; ++n)
                    acc[m][n] = __builtin_amdgcn_mfma_f32_16x16x32_bf16(
                        a[m][kk], b[n][kk], acc[m][n], 0, 0, 0);
    }

    const int rl = (lane >> 4) * 4;
    const int cl = lane & 15;
    #pragma unroll
    for (int m = 0; m < 4; ++m)
        #pragma unroll
        for (int rr = 0; rr < 4; ++rr) {
            const int srow = wr * 64 + m * 16 + rl + rr;
            if (tbase + srow < n_e) {
                _Float16* drow = delta + (size_t)(prow0 + srow) * F_OUT + o0 + wc * 64 + cl;
                #pragma unroll
                for (int n = 0; n < 4; ++n)
                    drow[n * 16] = (_Float16)acc[m][n][rr];
            }
        }
}

// ---------------- combine: out[tok] = cf0*delta[p0] + cf1*delta[p1] ----------------
__global__ __launch_bounds__(256) void combine_kernel(
    const _Float16* __restrict__ delta, const int* __restrict__ pos,
    const float* __restrict__ coeffs, const int* __restrict__ pbase,
    float* __restrict__ out)
{
    const int tok = blockIdx.x;
    const int id0 = pos[tok * 2 + 0];
    const int id1 = pos[tok * 2 + 1];
    const float cf0 = coeffs[id0];
    const float cf1 = coeffs[id1];
    const int r0 = pbase[id0 >> 13] + (id0 & (T_TOK - 1));
    const int r1 = pbase[id1 >> 13] + (id1 & (T_TOK - 1));
    const int c  = threadIdx.x * 8;

    const half8 a = *(const half8*)(delta + (size_t)r0 * F_OUT + c);
    const half8 b = *(const half8*)(delta + (size_t)r1 * F_OUT + c);
    float4 o0, o1;
    o0.x = cf0 * (float)a[0] + cf1 * (float)b[0];
    o0.y = cf0 * (float)a[1] + cf1 * (float)b[1];
    o0.z = cf0 * (float)a[2] + cf1 * (float)b[2];
    o0.w = cf0 * (float)a[3] + cf1 * (float)b[3];
    o1.x = cf0 * (float)a[4] + cf1 * (float)b[4];
    o1.y = cf0 * (float)a[5] + cf1 * (float)b[5];
    o1.z = cf0 * (float)a[6] + cf1 * (float)b[6];
    o1.w = cf0 * (float)a[7] + cf1 * (float)b[7];
    float* op = out + (size_t)tok * F_OUT + c;
    *(float4*)(op)     = o0;
    *(float4*)(op + 4) = o1;
}

extern "C" void kernel_launch(void* const* d_in, const int* in_sizes, int n_in,
                              void* d_out, int out_size, void* d_ws, size_t ws_size,
                              hipStream_t stream) {
    const float* x      = (const float*)d_in[0];
    const float* protos = (const float*)d_in[1];
    const float* W      = (const float*)d_in[2];
    const int*   scal   = (const int*)d_in[3];
    float* out = (float*)d_out;

    char* ws = (char*)d_ws;
    int*      counts = (int*)(ws + 0);
    int*      pbase  = (int*)(ws + 64);
    int*      ntiles = (int*)(ws + 128);
    int*      desc   = (int*)(ws + 256);
    int*      pos    = (int*)(ws + 65536);
    int*      lists  = (int*)(ws + 262144);
    float*    coeffs = (float*)(ws + 524288);
    ushort*   xb     = (ushort*)(ws + (1ull << 20));
    ushort*   Wb     = (ushort*)(ws + (36ull << 20));
    _Float16* delta  = (_Float16*)(ws + (104ull << 20));

    hipMemsetAsync(counts, 0, N_EXP * sizeof(int), stream);

    cvt_kernel<<<2048, 256, 0, stream>>>(W, Wb, N_EXP * F_OUT * F_IN / 8);
    route_kernel<<<T_TOK / RT_TPB, 256, 0, stream>>>(x, protos, scal, xb, counts, lists, coeffs, pos);
    plan_kernel<<<1, 64, 0, stream>>>(counts, pbase, ntiles, desc);

    dim3 grid(MAXTILES, F_OUT / 128);
    gemm_kernel<<<grid, 256, 0, stream>>>(xb, Wb, counts, lists, pbase, ntiles, desc, delta);

    combine_kernel<<<T_TOK, 256, 0, stream>>>(delta, pos, coeffs, pbase, out);
}

// Round 7
// 300.297 us; speedup vs baseline: 3.4932x; 1.1291x over previous
//
#include <hip/hip_runtime.h>

#define T_TOK 8192
#define F_IN  2048
#define F_OUT 2048
#define N_EXP 8
#define NKS   (F_IN / 64)      // 32 K-steps of 64
#define MAXTILES 144
#define RT_TPB 16              // tokens per routing block

typedef __attribute__((ext_vector_type(8))) short    short8;
typedef __attribute__((ext_vector_type(4))) float    f32x4;
typedef __attribute__((ext_vector_type(8))) _Float16 half8;
typedef unsigned short ushort;

#define AS1 __attribute__((address_space(1)))
#define AS3 __attribute__((address_space(3)))
#define GLOAD16(g, l) __builtin_amdgcn_global_load_lds((const AS1 unsigned int*)(g), \
                                                       (AS3 unsigned int*)(l), 16, 0, 0)

__device__ inline ushort f2bf(float f) {   // RNE
    unsigned u = __float_as_uint(f);
    u += 0x7FFFu + ((u >> 16) & 1u);
    return (ushort)(u >> 16);
}

// ---------------- fp32 -> bf16 bulk convert (W) ----------------
__global__ __launch_bounds__(256) void cvt_kernel(const float* __restrict__ in,
                                                  ushort* __restrict__ out, int n8) {
    for (int i = blockIdx.x * 256 + threadIdx.x; i < n8; i += gridDim.x * 256) {
        const float4 a = ((const float4*)in)[i * 2 + 0];
        const float4 b = ((const float4*)in)[i * 2 + 1];
        uint4 v;
        v.x = f2bf(a.x) | ((unsigned)f2bf(a.y) << 16);
        v.y = f2bf(a.z) | ((unsigned)f2bf(a.w) << 16);
        v.z = f2bf(b.x) | ((unsigned)f2bf(b.y) << 16);
        v.w = f2bf(b.z) | ((unsigned)f2bf(b.w) << 16);
        ((uint4*)out)[i] = v;
    }
}

// ---------------- routing + fused x->bf16, block-aggregated atomics ----------------
__device__ inline void top2_store(const float* s, int ti, float sc,
                                  int* sh_ei, float (*sh_cf)[2]) {
    float v0 = -1.f; int i0 = 0;
    #pragma unroll
    for (int e = 0; e < N_EXP; ++e) {
        const float a = fabsf(s[e]);
        if (a > v0) { v0 = a; i0 = e; }
    }
    float v1 = -1.f; int i1 = 0;
    #pragma unroll
    for (int e = 0; e < N_EXP; ++e) {
        const float a = fabsf(s[e]);
        if (e != i0 && a > v1) { v1 = a; i1 = e; }
    }
    const float ex  = expf(v1 - v0);
    const float inv = 1.f / (1.f + ex);
    sh_ei[ti]    = i0 | (i1 << 16);
    sh_cf[ti][0] = sc * inv;
    sh_cf[ti][1] = sc * ex * inv;
}

__global__ __launch_bounds__(256) void route_kernel(
    const float* __restrict__ x, const float* __restrict__ protos,
    const int* __restrict__ scaling, ushort* __restrict__ xb,
    int* __restrict__ counts, int* __restrict__ lists, float* __restrict__ coeffs,
    int* __restrict__ pos)
{
    __shared__ int   sh_ei[RT_TPB];
    __shared__ float sh_cf[RT_TPB][2];
    __shared__ int   sh_base[N_EXP];

    const int wave = threadIdx.x >> 6;
    const int lane = threadIdx.x & 63;
    const float sc = (float)(*scaling);

    for (int pr = 0; pr < 2; ++pr) {
        const int ti0  = wave * 4 + pr * 2;
        const int tok0 = blockIdx.x * RT_TPB + ti0;
        const float* xr0 = x  + (size_t)tok0 * F_IN;
        const float* xr1 = xr0 + F_IN;
        ushort*      xo0 = xb + (size_t)tok0 * F_IN;
        ushort*      xo1 = xo0 + F_IN;

        float s0[N_EXP] = {}, s1[N_EXP] = {};
        for (int c = 0; c < F_IN / 256; ++c) {
            const int off = c * 256 + lane * 4;
            const float4 a = *(const float4*)(xr0 + off);
            const float4 b = *(const float4*)(xr1 + off);
            uint2 ba, bb;
            ba.x = f2bf(a.x) | ((unsigned)f2bf(a.y) << 16);
            ba.y = f2bf(a.z) | ((unsigned)f2bf(a.w) << 16);
            bb.x = f2bf(b.x) | ((unsigned)f2bf(b.y) << 16);
            bb.y = f2bf(b.z) | ((unsigned)f2bf(b.w) << 16);
            *(uint2*)(xo0 + off) = ba;
            *(uint2*)(xo1 + off) = bb;
            #pragma unroll
            for (int e = 0; e < N_EXP; ++e) {
                const float4 pv = *(const float4*)(protos + e * F_IN + off);
                s0[e] += a.x * pv.x + a.y * pv.y + a.z * pv.z + a.w * pv.w;
                s1[e] += b.x * pv.x + b.y * pv.y + b.z * pv.z + b.w * pv.w;
            }
        }
        #pragma unroll
        for (int e = 0; e < N_EXP; ++e) {
            float v0 = s0[e], v1 = s1[e];
            #pragma unroll
            for (int off = 32; off; off >>= 1) {
                v0 += __shfl_down(v0, off, 64);
                v1 += __shfl_down(v1, off, 64);
            }
            s0[e] = v0; s1[e] = v1;
        }
        if (lane == 0) {
            top2_store(s0, ti0,     sc, sh_ei, sh_cf);
            top2_store(s1, ti0 + 1, sc, sh_ei, sh_cf);
        }
    }
    __syncthreads();

    if (threadIdx.x < 64) {
        const int  p      = threadIdx.x;
        const bool active = p < RT_TPB * 2;
        const int  ti = p >> 1, j = p & 1;
        const int  e  = active ? ((sh_ei[ti] >> (j * 16)) & 0xffff) : 0xff;
        int rank = 0;
        #pragma unroll
        for (int ee = 0; ee < N_EXP; ++ee) {
            const unsigned long long m = __ballot(active && (e == ee));
            if (e == ee)
                rank = __popcll(m & ((1ull << p) - 1ull));
            if (p == ee && m != 0ull)
                sh_base[ee] = atomicAdd(&counts[ee], (int)__popcll(m));
        }
        if (active) {
            const int position = sh_base[e] + rank;
            const int gidx  = e * T_TOK + position;
            const int token = blockIdx.x * RT_TPB + ti;
            lists [gidx] = token;
            coeffs[gidx] = sh_cf[ti][j];
            pos[token * 2 + j] = gidx;
        }
    }
}

// ---------------- plan: prefix bases + flat tile descriptors ----------------
__global__ void plan_kernel(const int* __restrict__ counts, int* __restrict__ pbase,
                            int* __restrict__ ntiles, int* __restrict__ desc) {
    if (threadIdx.x == 0) {
        int pb = 0, t = 0;
        for (int e = 0; e < N_EXP; ++e) {
            pbase[e] = pb;
            const int ne = counts[e];
            const int nt = (ne + 127) >> 7;
            for (int i = 0; i < nt; ++i) desc[t++] = (e << 8) | i;
            pb += ne;
        }
        *ntiles = t;
    }
}

// ---- grouped bf16 GEMM, 128x256, BK=64, 2-phase, swizzled LDS, XCD-swizzled grid ----
__global__ __launch_bounds__(256, 2) void gemm_kernel(
    const ushort* __restrict__ xb, const ushort* __restrict__ Wb,
    const int* __restrict__ counts, const int* __restrict__ lists,
    const int* __restrict__ pbase, const int* __restrict__ ntiles,
    const int* __restrict__ desc, _Float16* __restrict__ delta)
{
    // hardware id -> logical (tile-major, o0-minor) with per-XCD contiguous chunks.
    // nwg = MAXTILES*8 = 1152, 1152 % 8 == 0 -> simple bijection is safe.
    const int hw = blockIdx.x;
    const int l  = (hw & 7) * MAXTILES + (hw >> 3);
    const int ti = l >> 3;                 // tile index into desc
    const int oi = l & 7;                  // o0 block (256 cols)
    if (ti >= *ntiles) return;

    const int d     = desc[ti];
    const int e     = d >> 8;
    const int tile  = d & 255;
    const int n_e   = counts[e];
    const int tbase = tile << 7;
    const int o0    = oi * 256;
    const int prow0 = pbase[e] + tbase;

    __shared__ __align__(16) ushort As[128 * 64];   // 16 KiB
    __shared__ __align__(16) ushort Bs[256 * 64];   // 32 KiB

    const int tid  = threadIdx.x;
    const int lane = tid & 63;
    const int wid  = tid >> 6;
    const int wr   = wid >> 1, wc = wid & 1;

    // ---- staging: per-lane pre-swizzled global src, linear LDS dest ----
    const int ksrc = ((lane & 7) ^ (lane >> 3)) * 8;
    const ushort* srcA[4];
    #pragma unroll
    for (int g = 0; g < 4; ++g) {
        const int row  = g * 32 + wid * 8 + (lane >> 3);
        const int slot = min(tbase + row, n_e - 1);
        srcA[g] = xb + (size_t)lists[e * T_TOK + slot] * F_IN + ksrc;
    }
    const ushort* srcB = Wb + ((size_t)(e * F_OUT + o0 + wid * 8 + (lane >> 3))) * F_IN + ksrc;

    // ---- fragment read bases (same XOR on read side) ----
    const int octx8 = ((lane >> 4) ^ (lane & 7)) * 8;
    const int ai    = (wr * 64  + (lane & 15)) * 64 + octx8;
    const int bi    = (wc * 128 + (lane & 15)) * 64 + octx8;

    f32x4 acc[4][8] = {};

    for (int ks = 0; ks < NKS; ++ks) {
        __syncthreads();                       // prev-step LDS reads complete
        #pragma unroll
        for (int g = 0; g < 4; ++g) {
            GLOAD16(srcA[g], As + (g * 32 + wid * 8) * 64);
            srcA[g] += 64;
        }
        #pragma unroll
        for (int g = 0; g < 8; ++g)
            GLOAD16(srcB + (size_t)g * 32 * F_IN, Bs + (g * 32 + wid * 8) * 64);
        srcB += 64;
        __syncthreads();                       // staged data visible

        short8 a[4][2], b[8][2];
        #pragma unroll
        for (int m = 0; m < 4; ++m) {
            a[m][0] = *(const short8*)(As + (ai + m * 1024));
            a[m][1] = *(const short8*)(As + ((ai + m * 1024) ^ 32));
        }
        #pragma unroll
        for (int n = 0; n < 8; ++n) {
            b[n][0] = *(const short8*)(Bs + (bi + n * 1024));
            b[n][1] = *(const short8*)(Bs + ((bi + n * 1024) ^ 32));
        }
        #pragma unroll
        for (int kk = 0; kk < 2; ++kk)
            #pragma unroll
            for (int m = 0; m < 4; ++m)
                #pragma unroll
                for (int n = 0; n < 8; ++n)
                    acc[m][n] = __builtin_amdgcn_mfma_f32_16x16x32_bf16(
                        a[m][kk], b[n][kk], acc[m][n], 0, 0, 0);
    }

    // ---- epilogue: single-writer fp16 delta rows ----
    const int rl = (lane >> 4) * 4;
    const int cl = lane & 15;
    #pragma unroll
    for (int m = 0; m < 4; ++m)
        #pragma unroll
        for (int rr = 0; rr < 4; ++rr) {
            const int srow = wr * 64 + m * 16 + rl + rr;
            if (tbase + srow < n_e) {
                _Float16* drow = delta + (size_t)(prow0 + srow) * F_OUT + o0 + wc * 128 + cl;
                #pragma unroll
                for (int n = 0; n < 8; ++n)
                    drow[n * 16] = (_Float16)acc[m][n][rr];
            }
        }
}

// ---------------- combine: out[tok] = cf0*delta[p0] + cf1*delta[p1] ----------------
__global__ __launch_bounds__(256) void combine_kernel(
    const _Float16* __restrict__ delta, const int* __restrict__ pos,
    const float* __restrict__ coeffs, const int* __restrict__ pbase,
    float* __restrict__ out)
{
    const int tok = blockIdx.x;
    const int id0 = pos[tok * 2 + 0];
    const int id1 = pos[tok * 2 + 1];
    const float cf0 = coeffs[id0];
    const float cf1 = coeffs[id1];
    const int r0 = pbase[id0 >> 13] + (id0 & (T_TOK - 1));
    const int r1 = pbase[id1 >> 13] + (id1 & (T_TOK - 1));
    const int c  = threadIdx.x * 8;

    const half8 a = *(const half8*)(delta + (size_t)r0 * F_OUT + c);
    const half8 b = *(const half8*)(delta + (size_t)r1 * F_OUT + c);
    float4 o0, o1;
    o0.x = cf0 * (float)a[0] + cf1 * (float)b[0];
    o0.y = cf0 * (float)a[1] + cf1 * (float)b[1];
    o0.z = cf0 * (float)a[2] + cf1 * (float)b[2];
    o0.w = cf0 * (float)a[3] + cf1 * (float)b[3];
    o1.x = cf0 * (float)a[4] + cf1 * (float)b[4];
    o1.y = cf0 * (float)a[5] + cf1 * (float)b[5];
    o1.z = cf0 * (float)a[6] + cf1 * (float)b[6];
    o1.w = cf0 * (float)a[7] + cf1 * (float)b[7];
    float* op = out + (size_t)tok * F_OUT + c;
    *(float4*)(op)     = o0;
    *(float4*)(op + 4) = o1;
}

extern "C" void kernel_launch(void* const* d_in, const int* in_sizes, int n_in,
                              void* d_out, int out_size, void* d_ws, size_t ws_size,
                              hipStream_t stream) {
    const float* x      = (const float*)d_in[0];
    const float* protos = (const float*)d_in[1];
    const float* W      = (const float*)d_in[2];
    const int*   scal   = (const int*)d_in[3];
    float* out = (float*)d_out;

    char* ws = (char*)d_ws;
    int*      counts = (int*)(ws + 0);
    int*      pbase  = (int*)(ws + 64);
    int*      ntiles = (int*)(ws + 128);
    int*      desc   = (int*)(ws + 256);
    int*      pos    = (int*)(ws + 65536);
    int*      lists  = (int*)(ws + 262144);
    float*    coeffs = (float*)(ws + 524288);
    ushort*   xb     = (ushort*)(ws + (1ull << 20));
    ushort*   Wb     = (ushort*)(ws + (36ull << 20));
    _Float16* delta  = (_Float16*)(ws + (104ull << 20));

    hipMemsetAsync(counts, 0, N_EXP * sizeof(int), stream);

    cvt_kernel<<<2048, 256, 0, stream>>>(W, Wb, N_EXP * F_OUT * F_IN / 8);
    route_kernel<<<T_TOK / RT_TPB, 256, 0, stream>>>(x, protos, scal, xb, counts, lists, coeffs, pos);
    plan_kernel<<<1, 64, 0, stream>>>(counts, pbase, ntiles, desc);

    gemm_kernel<<<MAXTILES * 8, 256, 0, stream>>>(xb, Wb, counts, lists, pbase, ntiles, desc, delta);

    combine_kernel<<<T_TOK, 256, 0, stream>>>(delta, pos, coeffs, pbase, out);
}